// Round 9
// baseline (3665.025 us; speedup 1.0000x reference)
//
#include <hip/hip_runtime.h>
#include <math.h>

#define AGENTS __HIP_MEMORY_SCOPE_AGENT
typedef unsigned long long u64x;

constexpr int   CB   = 16;      // batches
constexpr int   CN   = 16384;   // rows per batch
constexpr float LOG7 = 1.9459101090932196f;
constexpr float EPST = 1e-8f;

// ---- u64 stamp region ----
constexpr size_t ST1 = 0;        // [16][16][2] phase-0 (mx,se), epoch==1
constexpr size_t NST = 512;

// ---- float offsets ----
constexpr size_t OFF_LG  = 1024;      // [16][16384] logits
constexpr size_t OFF_P   = 263168;    // [16][16384][8]  p rows: p0..p6, aval
constexpr size_t OFF_PN  = 2360320;   // [16][16384][8]  gp accumulator rows
constexpr size_t OFF_WQT = 4457472;   // [64][64]
constexpr size_t OFF_WIH = 4461568;   // [64][192]
constexpr size_t OFF_WHH = 4473856;   // [64][192]
constexpr size_t OFF_F1T = 4486144;   // [64][128]
constexpr size_t OFF_F2T = 4494336;   // [128][64]
constexpr size_t OFF_K   = 4502528;   // [16][16384][64]
constexpr size_t OFF_V   = 21279744;  // [16][16384][64]

__device__ __forceinline__ u64x pkf(float v, unsigned e) {
  return ((u64x)e << 32) | (u64x)__float_as_uint(v);
}
__device__ __forceinline__ void st_rlx(u64x* p, u64x v) {
  __hip_atomic_store(p, v, __ATOMIC_RELAXED, AGENTS);
}
__device__ __forceinline__ u64x ld_rlx(const u64x* p) {
  return __hip_atomic_load(const_cast<u64x*>(p), __ATOMIC_RELAXED, AGENTS);
}
// Lesson (R5+R7, both deadlocked): polling MUST use sc1 loads. No sc0 shortcuts.
__device__ __forceinline__ float poll_sc1(const u64x* p, unsigned e) {
  u64x q;
  do {
    q = ld_rlx(p);
    if ((unsigned)(q >> 32) != e) __builtin_amdgcn_s_sleep(2);
  } while ((unsigned)(q >> 32) != e);
  return __uint_as_float((unsigned)q);
}
__device__ __forceinline__ float frcp(float x) {
  float r; asm("v_rcp_f32 %0, %1" : "=v"(r) : "v"(x)); return r;
}
__device__ __forceinline__ float wsum64(float v) {
#pragma unroll
  for (int m = 1; m < 64; m <<= 1) v += __shfl_xor(v, m, 64);
  return v;
}
__device__ __forceinline__ float dot4(float4 a, float4 b) {
  return a.x * b.x + a.y * b.y + a.z * b.z + a.w * b.w;
}

__global__ void prep_kernel(const float* __restrict__ Wq, const float* __restrict__ Wih,
                            const float* __restrict__ Whh, const float* __restrict__ f1,
                            const float* __restrict__ f2, float* __restrict__ w) {
  size_t idx = blockIdx.x * blockDim.x + threadIdx.x;
  size_t stride = (size_t)gridDim.x * blockDim.x;
  u64x* st = reinterpret_cast<u64x*>(w);
  for (size_t i = idx; i < NST; i += stride) st_rlx(st + i, 0ULL);
  for (size_t i = idx; i < 64 * 64; i += stride) {
    int d = i / 64, j = i % 64;
    w[OFF_WQT + j * 64 + d] = Wq[d * 64 + j];
  }
  for (size_t i = idx; i < 192 * 64; i += stride) {
    int o = i / 64, j = i % 64;
    w[OFF_WIH + j * 192 + o] = Wih[o * 64 + j];
    w[OFF_WHH + j * 192 + o] = Whh[o * 64 + j];
  }
  for (size_t i = idx; i < 128 * 64; i += stride) {
    int o = i / 64, j = i % 64;
    w[OFF_F1T + j * 128 + o] = f1[o * 64 + j];
  }
  for (size_t i = idx; i < 64 * 128; i += stride) {
    int d = i / 128, j = i % 128;
    w[OFF_F2T + j * 64 + d] = f2[d * 128 + j];
  }
}

__launch_bounds__(1024, 4)
__global__ void slot_attn_kernel(
    const float* __restrict__ inputs, const float* __restrict__ sinit,
    const float* __restrict__ smu, const float* __restrict__ slsig,
    const float* __restrict__ Wk, const float* __restrict__ Wv,
    const float* __restrict__ gbih, const float* __restrict__ gbhh,
    const float* __restrict__ fc1b, const float* __restrict__ fc2b,
    const float* __restrict__ lin_g, const float* __restrict__ lin_b,
    const float* __restrict__ lsl_g, const float* __restrict__ lsl_b,
    const float* __restrict__ lff_g, const float* __restrict__ lff_b,
    const float* __restrict__ wi_W, const float* __restrict__ wi_b,
    const float* __restrict__ wsW, const float* __restrict__ wsB,
    float* __restrict__ out, float* __restrict__ w) {
  __shared__ float s_slots[448];
  __shared__ float s_snl[448];
  __shared__ float s_q[448];
  __shared__ float s_scr1[1344];
  __shared__ float s_scr2[1344];
  __shared__ float s_updl[448];
  __shared__ float s_T[8192];       // [1024][8]
  __shared__ float s_pupd[7168];    // [16][7][64]
  __shared__ float s_z[48];         // z history [6][8]
  __shared__ float s_eb[8];         // exp(log_b)
  __shared__ float s_rb[8];         // 1/exp(log_b)
  __shared__ float s_gvl[8];
  __shared__ float s_q2[8];
  __shared__ float s_wl[8];
  __shared__ float s_redw[128];     // [16][8]
  __shared__ float s_gath[32];
  __shared__ float s_misc[4];

  const int tid = threadIdx.x;
  const int lane = tid & 63, wid = tid >> 6;
  const int bb = blockIdx.x & 15;   // batch
  const int ib16 = blockIdx.x >> 4; // 0..15 producer chunk within batch
  u64x* st = reinterpret_cast<u64x*>(w);

  // ================= phase 0 (all 256 blocks): LN + k/v/logit =================
  {
    const size_t grow = (size_t)bb * CN + (size_t)ib16 * 1024 + tid;
    const float* xin = inputs + grow * 64;
    float4 xa[16];
#pragma unroll
    for (int c = 0; c < 16; ++c) xa[c] = reinterpret_cast<const float4*>(xin)[c];
    float s1 = 0;
#pragma unroll
    for (int c = 0; c < 16; ++c) s1 += xa[c].x + xa[c].y + xa[c].z + xa[c].w;
    float mn = s1 * (1.f / 64.f);
    float s2 = 0;
#pragma unroll
    for (int c = 0; c < 16; ++c) {
      float dx = xa[c].x - mn, dy = xa[c].y - mn, dz = xa[c].z - mn, dw = xa[c].w - mn;
      s2 += dx * dx + dy * dy + dz * dz + dw * dw;
    }
    float rs = rsqrtf(s2 * (1.f / 64.f) + 1e-5f);
#pragma unroll
    for (int c = 0; c < 16; ++c) {
      float4 g4 = reinterpret_cast<const float4*>(lin_g)[c];
      float4 b4 = reinterpret_cast<const float4*>(lin_b)[c];
      xa[c].x = (xa[c].x - mn) * rs * g4.x + b4.x;
      xa[c].y = (xa[c].y - mn) * rs * g4.y + b4.y;
      xa[c].z = (xa[c].z - mn) * rs * g4.z + b4.z;
      xa[c].w = (xa[c].w - mn) * rs * g4.w + b4.w;
    }
    float lg = wi_b[0];
#pragma unroll
    for (int c = 0; c < 16; ++c) lg += dot4(xa[c], reinterpret_cast<const float4*>(wi_W)[c]);
    w[OFF_LG + grow] = lg;
#pragma unroll 1
    for (int half = 0; half < 2; ++half) {
      const float* W = half ? Wv : Wk;
      float* ob = w + (half ? OFF_V : OFF_K) + grow * 64;
#pragma unroll 1
      for (int oc = 0; oc < 8; ++oc) {
        float acc[8] = {0, 0, 0, 0, 0, 0, 0, 0};
#pragma unroll
        for (int c = 0; c < 16; ++c) {
          float4 xv = xa[c];
#pragma unroll
          for (int o8 = 0; o8 < 8; ++o8) {
            float4 w4 = reinterpret_cast<const float4*>(W + (size_t)(oc * 8 + o8) * 64)[c];
            acc[o8] += dot4(xv, w4);
          }
        }
        reinterpret_cast<float4*>(ob + oc * 8)[0] = make_float4(acc[0], acc[1], acc[2], acc[3]);
        reinterpret_cast<float4*>(ob + oc * 8)[1] = make_float4(acc[4], acc[5], acc[6], acc[7]);
      }
    }
    // block-local softmax stats
    float mx = lg;
#pragma unroll
    for (int m = 1; m < 64; m <<= 1) mx = fmaxf(mx, __shfl_xor(mx, m, 64));
    float se = wsum64(__expf(lg - mx));
    if (lane == 0) { s_redw[wid * 8 + 0] = mx; s_redw[wid * 8 + 1] = se; }
    asm volatile("s_waitcnt vmcnt(0)" ::: "memory");  // this wave's stores issued
    __syncthreads();                                  // all waves' stores issued
    if (wid == 0) {
      __threadfence();  // RELEASE: write back dirty k/v/lg L2 lines (cache-wide)
      float m0 = (lane < 16) ? s_redw[lane * 8 + 0] : -1e30f;
      float e0 = (lane < 16) ? s_redw[lane * 8 + 1] : 0.f;
#pragma unroll
      for (int mm = 1; mm < 16; mm <<= 1) {
        float m1 = __shfl_xor(m0, mm, 64), e1 = __shfl_xor(e0, mm, 64);
        float nm = fmaxf(m0, m1);
        e0 = e0 * __expf(m0 - nm) + e1 * __expf(m1 - nm);
        m0 = nm;
      }
      if (lane == 0) {
        u64x* sp = st + ST1 + (size_t)(bb * 16 + ib16) * 2;
        st_rlx(sp + 0, pkf(m0, 1u));
        st_rlx(sp + 1, pkf(e0, 1u));
      }
    }
  }

  if (blockIdx.x >= 16) return;     // 16 workers remain: worker bb == blockIdx

  // ---- gather stats (sc1), compute lse; then fence (inv stale L2 lines) ----
  if (wid == 0 && lane < 32) {
    int j = lane >> 1, f = lane & 1;
    s_gath[lane] = poll_sc1(st + ST1 + (size_t)(bb * 16 + j) * 2 + f, 1u);
  }
  __syncthreads();
  if (tid == 0) {
    float m = s_gath[0], se = s_gath[1];
#pragma unroll 1
    for (int j = 1; j < 16; ++j) {
      float mj = s_gath[j * 2], ej = s_gath[j * 2 + 1];
      float nm = fmaxf(m, mj);
      se = se * __expf(m - nm) + ej * __expf(mj - nm);
      m = nm;
    }
    s_misc[0] = m + __logf(se);
  }
  __syncthreads();
  const float lseA = s_misc[0];
  __threadfence();                  // ACQUIRE: invalidate stale k/v/lg/p lines
  __syncthreads();

  float* P = w + OFF_P  + (size_t)bb * CN * 8;   // thread-private rows r*1024+tid
  float* G = w + OFF_PN + (size_t)bb * CN * 8;

  // ---- block-internal reduce of 7 values over all 16384 rows ----
  auto red7 = [&](float (&es)[7], float* dst, bool div_eb) {
#pragma unroll
    for (int m = 1; m < 64; m <<= 1) {
#pragma unroll
      for (int s = 0; s < 7; ++s) es[s] += __shfl_xor(es[s], m, 64);
    }
    if (lane == 0) {
#pragma unroll
      for (int s = 0; s < 7; ++s) s_redw[wid * 8 + s] = es[s];
    }
    __syncthreads();
    if (wid == 0 && lane < 7) {
      float tot = 0.f;
#pragma unroll
      for (int j = 0; j < 16; ++j) tot += s_redw[j * 8 + lane];
      dst[lane] = div_eb ? (s_eb[lane] / tot) : tot;
    }
    __syncthreads();
  };

  // factored sinkhorn forward: 5 iters; z history in s_z
  auto fwd5 = [&]() {
#pragma unroll 1
    for (int i = 1; i <= 5; ++i) {
      float z0 = s_z[(i - 1) * 8 + 0], z1 = s_z[(i - 1) * 8 + 1], z2 = s_z[(i - 1) * 8 + 2],
            z3 = s_z[(i - 1) * 8 + 3], z4 = s_z[(i - 1) * 8 + 4], z5 = s_z[(i - 1) * 8 + 5],
            z6 = s_z[(i - 1) * 8 + 6];
      float es[7] = {0, 0, 0, 0, 0, 0, 0};
#pragma unroll 2
      for (int r = 0; r < 16; ++r) {
        const float* pr = P + ((size_t)r * 1024 + tid) * 8;
        float4 pa = *reinterpret_cast<const float4*>(pr);
        float4 pb = *reinterpret_cast<const float4*>(pr + 4);
        float E0 = __expf(pa.x), E1 = __expf(pa.y), E2 = __expf(pa.z), E3 = __expf(pa.w);
        float E4 = __expf(pb.x), E5 = __expf(pb.y), E6 = __expf(pb.z);
        float t = E0 * z0 + E1 * z1 + E2 * z2 + E3 * z3 + E4 * z4 + E5 * z5 + E6 * z6;
        float eu = pb.w * frcp(t);
        es[0] += E0 * eu; es[1] += E1 * eu; es[2] += E2 * eu; es[3] += E3 * eu;
        es[4] += E4 * eu; es[5] += E5 * eu; es[6] += E6 * eu;
      }
      red7(es, &s_z[i * 8], true);
    }
  };

  // slot phase common: LN(slots)->snl, q into LDS, eb/rb
  auto slot_common = [&]() {
    if (wid < 7) {
      float h = s_slots[wid * 64 + lane];
      float m = wsum64(h) * (1.f / 64.f);
      float d0 = h - m;
      float va = wsum64(d0 * d0) * (1.f / 64.f);
      float sn = d0 * rsqrtf(va + 1e-5f) * lsl_g[lane] + lsl_b[lane];
      s_snl[wid * 64 + lane] = sn;
      float pw = wsum64(sn * wsW[lane]);
      if (lane == 0) s_wl[wid] = pw + wsB[0];
    }
    __syncthreads();
    if (tid < 448) {
      int s = tid >> 6, dd = tid & 63;
      float acc = 0;
#pragma unroll 4
      for (int j = 0; j < 64; ++j) acc += s_snl[s * 64 + j] * w[OFF_WQT + j * 64 + dd];
      s_q[s * 64 + dd] = acc;
    }
    __syncthreads();
    if (wid < 7) {
      float qv = s_q[wid * 64 + lane];
      float q2 = wsum64(qv * qv);
      if (lane == 0) s_q2[wid] = q2;
    }
    if (tid == 0) {
      float mx = -1e30f;
#pragma unroll
      for (int s = 0; s < 7; ++s) mx = fmaxf(mx, s_wl[s]);
      float se = 0;
#pragma unroll
      for (int s = 0; s < 7; ++s) se += __expf(s_wl[s] - mx);
      float lse = mx + __logf(se);
#pragma unroll
      for (int s = 0; s < 7; ++s) {
        float ebv = __expf(s_wl[s] - lse + LOG7);
        s_eb[s] = ebv;
        s_rb[s] = 1.f / ebv;
      }
    }
    __syncthreads();
  };

  // init slots
  if (tid < 448) {
    int dd = tid & 63;
    s_slots[tid] = smu[dd] + __expf(slsig[dd]) * sinit[(size_t)bb * 448 + tid];
  }
  __syncthreads();
  slot_common();

#pragma unroll 1
  for (int it = 0; it < 3; ++it) {
    // ---- C rows: p = -cdist, aval in slot 7 ----
#pragma unroll 1
    for (int r = 0; r < 16; ++r) {
      const float* kb = w + OFF_K + ((size_t)bb * CN + (size_t)r * 1024 + tid) * 64;
      float k2 = 0, kq0 = 0, kq1 = 0, kq2 = 0, kq3 = 0, kq4 = 0, kq5 = 0, kq6 = 0;
#pragma unroll 4
      for (int c = 0; c < 16; ++c) {
        float4 kk = *reinterpret_cast<const float4*>(kb + c * 4);
        k2  += dot4(kk, kk);
        kq0 += dot4(kk, *reinterpret_cast<const float4*>(&s_q[0 * 64 + c * 4]));
        kq1 += dot4(kk, *reinterpret_cast<const float4*>(&s_q[1 * 64 + c * 4]));
        kq2 += dot4(kk, *reinterpret_cast<const float4*>(&s_q[2 * 64 + c * 4]));
        kq3 += dot4(kk, *reinterpret_cast<const float4*>(&s_q[3 * 64 + c * 4]));
        kq4 += dot4(kk, *reinterpret_cast<const float4*>(&s_q[4 * 64 + c * 4]));
        kq5 += dot4(kk, *reinterpret_cast<const float4*>(&s_q[5 * 64 + c * 4]));
        kq6 += dot4(kk, *reinterpret_cast<const float4*>(&s_q[6 * 64 + c * 4]));
      }
      float p0 = -sqrtf(fmaxf(k2 + s_q2[0] - 2.f * kq0, 0.f) + 1e-12f);
      float p1 = -sqrtf(fmaxf(k2 + s_q2[1] - 2.f * kq1, 0.f) + 1e-12f);
      float p2 = -sqrtf(fmaxf(k2 + s_q2[2] - 2.f * kq2, 0.f) + 1e-12f);
      float p3 = -sqrtf(fmaxf(k2 + s_q2[3] - 2.f * kq3, 0.f) + 1e-12f);
      float p4 = -sqrtf(fmaxf(k2 + s_q2[4] - 2.f * kq4, 0.f) + 1e-12f);
      float p5 = -sqrtf(fmaxf(k2 + s_q2[5] - 2.f * kq5, 0.f) + 1e-12f);
      float p6 = -sqrtf(fmaxf(k2 + s_q2[6] - 2.f * kq6, 0.f) + 1e-12f);
      float lgr = w[OFF_LG + (size_t)bb * CN + (size_t)r * 1024 + tid];
      float av = 7.f * __expf(lgr - lseA);
      float* pw = P + ((size_t)r * 1024 + tid) * 8;
      *reinterpret_cast<float4*>(pw)     = make_float4(p0, p1, p2, p3);
      *reinterpret_cast<float4*>(pw + 4) = make_float4(p4, p5, p6, av);
    }
    if (tid < 8) s_z[tid] = 1.f;     // z0 = exp(v0) = 1
    __syncthreads();

    // ---- MESH: 4 iterations ----
#pragma unroll 1
    for (int ms = 0; ms < 4; ++ms) {
      fwd5();
      // pass A: g = gT*T, store into G rows [g0..g6, sum]; reduce -> gv5
      {
        float zm0 = s_z[32], zm1 = s_z[33], zm2 = s_z[34], zm3 = s_z[35],
              zm4 = s_z[36], zm5 = s_z[37], zm6 = s_z[38];
        float zf0 = s_z[40], zf1 = s_z[41], zf2 = s_z[42], zf3 = s_z[43],
              zf4 = s_z[44], zf5 = s_z[45], zf6 = s_z[46];
        float es[7] = {0, 0, 0, 0, 0, 0, 0};
#pragma unroll 2
        for (int r = 0; r < 16; ++r) {
          const float* pr = P + ((size_t)r * 1024 + tid) * 8;
          float4 pa = *reinterpret_cast<const float4*>(pr);
          float4 pb = *reinterpret_cast<const float4*>(pr + 4);
          float E0 = __expf(pa.x), E1 = __expf(pa.y), E2 = __expf(pa.z), E3 = __expf(pa.w);
          float E4 = __expf(pb.x), E5 = __expf(pb.y), E6 = __expf(pb.z);
          float t = E0 * zm0 + E1 * zm1 + E2 * zm2 + E3 * zm3 + E4 * zm4 + E5 * zm5 + E6 * zm6;
          float eu = pb.w * frcp(t);
          float T0 = E0 * eu * zf0, T1 = E1 * eu * zf1, T2 = E2 * eu * zf2,
                T3 = E3 * eu * zf3, T4 = E4 * eu * zf4, T5 = E5 * eu * zf5, T6 = E6 * eu * zf6;
          float g0 = -(__logf(T0 + EPST) + T0 * frcp(T0 + EPST)) * T0;
          float g1 = -(__logf(T1 + EPST) + T1 * frcp(T1 + EPST)) * T1;
          float g2 = -(__logf(T2 + EPST) + T2 * frcp(T2 + EPST)) * T2;
          float g3 = -(__logf(T3 + EPST) + T3 * frcp(T3 + EPST)) * T3;
          float g4 = -(__logf(T4 + EPST) + T4 * frcp(T4 + EPST)) * T4;
          float g5 = -(__logf(T5 + EPST) + T5 * frcp(T5 + EPST)) * T5;
          float g6 = -(__logf(T6 + EPST) + T6 * frcp(T6 + EPST)) * T6;
          float gs = g0 + g1 + g2 + g3 + g4 + g5 + g6;
          float* gr = G + ((size_t)r * 1024 + tid) * 8;
          *reinterpret_cast<float4*>(gr)     = make_float4(g0, g1, g2, g3);
          *reinterpret_cast<float4*>(gr + 4) = make_float4(g4, g5, g6, gs);
          es[0] += g0; es[1] += g1; es[2] += g2; es[3] += g3;
          es[4] += g4; es[5] += g5; es[6] += g6;
        }
        red7(es, s_gvl, false);
      }
      // backward stages i=5..1 (stage 1 folds the p update)
#pragma unroll 1
      for (int i = 5; i >= 1; --i) {
        float zm0 = s_z[(i - 1) * 8 + 0], zm1 = s_z[(i - 1) * 8 + 1], zm2 = s_z[(i - 1) * 8 + 2],
              zm3 = s_z[(i - 1) * 8 + 3], zm4 = s_z[(i - 1) * 8 + 4], zm5 = s_z[(i - 1) * 8 + 5],
              zm6 = s_z[(i - 1) * 8 + 6];
        float w0 = s_z[i * 8 + 0] * s_rb[0] * s_gvl[0], w1 = s_z[i * 8 + 1] * s_rb[1] * s_gvl[1],
              w2 = s_z[i * 8 + 2] * s_rb[2] * s_gvl[2], w3 = s_z[i * 8 + 3] * s_rb[3] * s_gvl[3],
              w4 = s_z[i * 8 + 4] * s_rb[4] * s_gvl[4], w5 = s_z[i * 8 + 5] * s_rb[5] * s_gvl[5],
              w6 = s_z[i * 8 + 6] * s_rb[6] * s_gvl[6];
        float es[7] = {0, 0, 0, 0, 0, 0, 0};
#pragma unroll 2
        for (int r = 0; r < 16; ++r) {
          float* pr = P + ((size_t)r * 1024 + tid) * 8;
          float* gr = G + ((size_t)r * 1024 + tid) * 8;
          float4 pa = *reinterpret_cast<const float4*>(pr);
          float4 pb = *reinterpret_cast<const float4*>(pr + 4);
          float4 ga = *reinterpret_cast<const float4*>(gr);
          float4 gb = *reinterpret_cast<const float4*>(gr + 4);
          float E0 = __expf(pa.x), E1 = __expf(pa.y), E2 = __expf(pa.z), E3 = __expf(pa.w);
          float E4 = __expf(pb.x), E5 = __expf(pb.y), E6 = __expf(pb.z);
          float t = E0 * zm0 + E1 * zm1 + E2 * zm2 + E3 * zm3 + E4 * zm4 + E5 * zm5 + E6 * zm6;
          float rt = frcp(t);
          float eui = pb.w * rt;
          float gu = (i == 5) ? gb.w : 0.f;
          float gz0 = -w0 * E0 * eui; gu += gz0;
          float gz1 = -w1 * E1 * eui; gu += gz1;
          float gz2 = -w2 * E2 * eui; gu += gz2;
          float gz3 = -w3 * E3 * eui; gu += gz3;
          float gz4 = -w4 * E4 * eui; gu += gz4;
          float gz5 = -w5 * E5 * eui; gu += gz5;
          float gz6 = -w6 * E6 * eui; gu += gz6;
          float a0 = ga.x + gz0, a1 = ga.y + gz1, a2 = ga.z + gz2, a3 = ga.w + gz3;
          float a4 = gb.x + gz4, a5 = gb.y + gz5, a6 = gb.z + gz6;
          float c = gu * rt;
          float gw0 = -c * E0 * zm0; a0 += gw0; es[0] += gw0;
          float gw1 = -c * E1 * zm1; a1 += gw1; es[1] += gw1;
          float gw2 = -c * E2 * zm2; a2 += gw2; es[2] += gw2;
          float gw3 = -c * E3 * zm3; a3 += gw3; es[3] += gw3;
          float gw4 = -c * E4 * zm4; a4 += gw4; es[4] += gw4;
          float gw5 = -c * E5 * zm5; a5 += gw5; es[5] += gw5;
          float gw6 = -c * E6 * zm6; a6 += gw6; es[6] += gw6;
          if (i > 1) {
            *reinterpret_cast<float4*>(gr)     = make_float4(a0, a1, a2, a3);
            *reinterpret_cast<float4*>(gr + 4) = make_float4(a4, a5, a6, 0.f);
          } else {
            *reinterpret_cast<float4*>(pr) =
                make_float4(pa.x - 5.f * a0, pa.y - 5.f * a1, pa.z - 5.f * a2, pa.w - 5.f * a3);
            *reinterpret_cast<float4*>(pr + 4) =
                make_float4(pb.x - 5.f * a4, pb.y - 5.f * a5, pb.z - 5.f * a6, pb.w);
          }
        }
        if (i > 1) red7(es, s_gvl, false);
      }
      if (tid < 7) s_z[tid] = s_z[40 + tid];   // warm-start z0 = z5
      __syncthreads();
    }

    // ---- final sinkhorn ----
    fwd5();

    // ---- updates = attn @ v in 16 passes; T recomputed per row ----
    {
      float zm0 = s_z[32], zm1 = s_z[33], zm2 = s_z[34], zm3 = s_z[35],
            zm4 = s_z[36], zm5 = s_z[37], zm6 = s_z[38];
      float zf0 = s_z[40], zf1 = s_z[41], zf2 = s_z[42], zf3 = s_z[43],
            zf4 = s_z[44], zf5 = s_z[45], zf6 = s_z[46];
      float ac0 = 0, ac1 = 0, ac2 = 0, ac3 = 0, ac4 = 0, ac5 = 0, ac6 = 0;
#pragma unroll 1
      for (int pass = 0; pass < 16; ++pass) {
        const float* pr = P + ((size_t)pass * 1024 + tid) * 8;
        float4 pa = *reinterpret_cast<const float4*>(pr);
        float4 pb = *reinterpret_cast<const float4*>(pr + 4);
        float E0 = __expf(pa.x), E1 = __expf(pa.y), E2 = __expf(pa.z), E3 = __expf(pa.w);
        float E4 = __expf(pb.x), E5 = __expf(pb.y), E6 = __expf(pb.z);
        float t = E0 * zm0 + E1 * zm1 + E2 * zm2 + E3 * zm3 + E4 * zm4 + E5 * zm5 + E6 * zm6;
        float eu = pb.w * frcp(t);
        float T0 = E0 * eu * zf0, T1 = E1 * eu * zf1, T2 = E2 * eu * zf2,
              T3 = E3 * eu * zf3, T4 = E4 * eu * zf4, T5 = E5 * eu * zf5, T6 = E6 * eu * zf6;
        if (it == 2) {
          size_t rowg = (size_t)pass * 1024 + tid;
          size_t ab = 7168 + (size_t)(bb * 7) * CN + rowg;
          out[ab] = T0; out[ab + (size_t)CN] = T1; out[ab + (size_t)2 * CN] = T2;
          out[ab + (size_t)3 * CN] = T3; out[ab + (size_t)4 * CN] = T4;
          out[ab + (size_t)5 * CN] = T5; out[ab + (size_t)6 * CN] = T6;
        }
        float* tr = &s_T[tid * 8];
        tr[0] = T0; tr[1] = T1; tr[2] = T2; tr[3] = T3; tr[4] = T4; tr[5] = T5; tr[6] = T6;
        __syncthreads();
        const float* vb = w + OFF_V +
            ((size_t)bb * CN + (size_t)pass * 1024 + wid * 64) * 64 + lane;
#pragma unroll 4
        for (int n = 0; n < 64; ++n) {
          float vv = __builtin_nontemporal_load(vb + (size_t)n * 64);
          const float* tq = &s_T[(wid * 64 + n) * 8];
          ac0 += tq[0] * vv; ac1 += tq[1] * vv; ac2 += tq[2] * vv;
          ac3 += tq[3] * vv; ac4 += tq[4] * vv; ac5 += tq[5] * vv; ac6 += tq[6] * vv;
        }
        __syncthreads();
      }
      s_pupd[(wid * 7 + 0) * 64 + lane] = ac0;
      s_pupd[(wid * 7 + 1) * 64 + lane] = ac1;
      s_pupd[(wid * 7 + 2) * 64 + lane] = ac2;
      s_pupd[(wid * 7 + 3) * 64 + lane] = ac3;
      s_pupd[(wid * 7 + 4) * 64 + lane] = ac4;
      s_pupd[(wid * 7 + 5) * 64 + lane] = ac5;
      s_pupd[(wid * 7 + 6) * 64 + lane] = ac6;
      __syncthreads();
      if (tid < 448) {
        float t = 0;
#pragma unroll
        for (int w16 = 0; w16 < 16; ++w16) t += s_pupd[w16 * 448 + tid];
        s_updl[tid] = t;
      }
      __syncthreads();
    }

    // ---- GRU cell + FF ----
    {
#pragma unroll 1
      for (int idx = tid; idx < 1344; idx += 1024) {
        int s = idx / 192, o = idx - s * 192;
        float g1 = gbih[o], g2 = gbhh[o];
#pragma unroll 4
        for (int j = 0; j < 64; ++j) {
          g1 += s_updl[s * 64 + j] * w[OFF_WIH + j * 192 + o];
          g2 += s_slots[s * 64 + j] * w[OFF_WHH + j * 192 + o];
        }
        s_scr1[s * 192 + o] = g1;
        s_scr2[s * 192 + o] = g2;
      }
      __syncthreads();
      if (tid < 448) {
        int s = tid >> 6, dd = tid & 63;
        float ir = s_scr1[s * 192 + dd],        hr = s_scr2[s * 192 + dd];
        float iz = s_scr1[s * 192 + 64 + dd],   hz = s_scr2[s * 192 + 64 + dd];
        float in_ = s_scr1[s * 192 + 128 + dd], hn = s_scr2[s * 192 + 128 + dd];
        float r = 1.f / (1.f + __expf(-(ir + hr)));
        float zz = 1.f / (1.f + __expf(-(iz + hz)));
        float nn = tanhf(in_ + r * hn);
        s_updl[s * 64 + dd] = (1.f - zz) * nn + zz * s_slots[s * 64 + dd];
      }
      __syncthreads();
      if (wid < 7) {
        float h = s_updl[wid * 64 + lane];
        float m = wsum64(h) * (1.f / 64.f);
        float d0 = h - m;
        float va = wsum64(d0 * d0) * (1.f / 64.f);
        s_snl[wid * 64 + lane] = d0 * rsqrtf(va + 1e-5f) * lff_g[lane] + lff_b[lane];
      }
      __syncthreads();
      if (tid < 896) {
        int s = tid >> 7, i2 = tid & 127;
        float a1 = fc1b[i2];
#pragma unroll 4
        for (int j = 0; j < 64; ++j) a1 += s_snl[s * 64 + j] * w[OFF_F1T + j * 128 + i2];
        s_scr1[s * 128 + i2] = fmaxf(a1, 0.f);
      }
      __syncthreads();
      if (tid < 448) {
        int s = tid >> 6, dd = tid & 63;
        float a2 = fc2b[dd];
#pragma unroll 4
        for (int i2 = 0; i2 < 128; ++i2) a2 += s_scr1[s * 128 + i2] * w[OFF_F2T + i2 * 64 + dd];
        s_slots[s * 64 + dd] = s_updl[s * 64 + dd] + a2;
      }
      __syncthreads();
    }
    if (it < 2) slot_common();
  }

  if (tid < 448) out[(size_t)bb * 448 + tid] = s_slots[tid];

  // flush dirty p/gp lines so no cross-replay staleness survives
  __syncthreads();
  if (wid == 0) __threadfence();
}

extern "C" void kernel_launch(void* const* d_in, const int* in_sizes, int n_in,
                              void* d_out, int out_size, void* d_ws, size_t ws_size,
                              hipStream_t stream) {
  (void)in_sizes; (void)n_in; (void)out_size; (void)ws_size;
  const float* inputs = (const float*)d_in[0];
  const float* sinit  = (const float*)d_in[1];
  const float* smu    = (const float*)d_in[2];
  const float* slsig  = (const float*)d_in[3];
  const float* Wq     = (const float*)d_in[4];
  const float* Wk     = (const float*)d_in[5];
  const float* Wv     = (const float*)d_in[6];
  const float* gWih   = (const float*)d_in[7];
  const float* gWhh   = (const float*)d_in[8];
  const float* gbih   = (const float*)d_in[9];
  const float* gbhh   = (const float*)d_in[10];
  const float* fc1W   = (const float*)d_in[11];
  const float* fc1b   = (const float*)d_in[12];
  const float* fc2W   = (const float*)d_in[13];
  const float* fc2b   = (const float*)d_in[14];
  const float* ling   = (const float*)d_in[15];
  const float* linb   = (const float*)d_in[16];
  const float* lslg   = (const float*)d_in[17];
  const float* lslb   = (const float*)d_in[18];
  const float* lffg   = (const float*)d_in[19];
  const float* lffb   = (const float*)d_in[20];
  const float* wiW    = (const float*)d_in[21];
  const float* wib    = (const float*)d_in[22];
  const float* wsW    = (const float*)d_in[23];
  const float* wsb    = (const float*)d_in[24];
  float* out = (float*)d_out;
  float* w   = (float*)d_ws;

  prep_kernel<<<dim3(64), dim3(256), 0, stream>>>(Wq, gWih, gWhh, fc1W, fc2W, w);
  slot_attn_kernel<<<dim3(256), dim3(1024), 0, stream>>>(
      inputs, sinit, smu, slsig, Wk, Wv, gbih, gbhh, fc1b, fc2b,
      ling, linb, lslg, lslb, lffg, lffb, wiW, wib, wsW, wsb, out, w);
}

// Round 11
// 2600.016 us; speedup vs baseline: 1.4096x; 1.4096x over previous
//
#include <hip/hip_runtime.h>
#include <math.h>

#define AGENTS __HIP_MEMORY_SCOPE_AGENT
typedef unsigned long long u64x;

constexpr int   CB   = 16;      // batches
constexpr int   CN   = 16384;   // rows per batch
constexpr float LOG7 = 1.9459101090932196f;
constexpr float EPST = 1e-8f;

// ---- u64 stamp regions (sc1-only transport; R5/R7/R10 rule: no sub-agent polling)
constexpr size_t ST1 = 0;        // [16][16][2]      phase-0 stats (mx,se), e==1
constexpr size_t ST2 = 512;      // [16][2][16][8]   sweep partials
constexpr size_t ST3 = 4608;     // [16][2][16][448] update partials
constexpr size_t ST4 = 233984;   // [16][2][16][256] mega backward partials (210 used)
constexpr size_t NST = 365056;

// ---- float offsets ----
constexpr size_t OFF_WQT = 730112;    // [64][64]
constexpr size_t OFF_WIH = 734208;    // [64][192]
constexpr size_t OFF_WHH = 746496;    // [64][192]
constexpr size_t OFF_F1T = 758784;    // [64][128]
constexpr size_t OFF_F2T = 766976;    // [128][64]
constexpr size_t OFF_K   = 775168;    // [16][16384][64]
constexpr size_t OFF_V   = 17552384;  // [16][16384][64]

__device__ __forceinline__ u64x pkf(float v, unsigned e) {
  return ((u64x)e << 32) | (u64x)__float_as_uint(v);
}
__device__ __forceinline__ void st_rlx(u64x* p, u64x v) {
  __hip_atomic_store(p, v, __ATOMIC_RELAXED, AGENTS);
}
__device__ __forceinline__ u64x ld_rlx(const u64x* p) {
  return __hip_atomic_load(const_cast<u64x*>(p), __ATOMIC_RELAXED, AGENTS);
}
__device__ __forceinline__ float poll_sc1(const u64x* p, unsigned e) {
  u64x q;
  do {
    q = ld_rlx(p);
    if ((unsigned)(q >> 32) != e) __builtin_amdgcn_s_sleep(2);
  } while ((unsigned)(q >> 32) != e);
  return __uint_as_float((unsigned)q);
}
__device__ __forceinline__ float wsum64(float v) {
#pragma unroll
  for (int m = 1; m < 64; m <<= 1) v += __shfl_xor(v, m, 64);
  return v;
}
__device__ __forceinline__ float dot4(float4 a, float4 b) {
  return a.x * b.x + a.y * b.y + a.z * b.z + a.w * b.w;
}

__global__ void prep_kernel(const float* __restrict__ Wq, const float* __restrict__ Wih,
                            const float* __restrict__ Whh, const float* __restrict__ f1,
                            const float* __restrict__ f2, float* __restrict__ w) {
  size_t idx = blockIdx.x * blockDim.x + threadIdx.x;
  size_t stride = (size_t)gridDim.x * blockDim.x;
  u64x* st = reinterpret_cast<u64x*>(w);
  for (size_t i = idx; i < NST; i += stride) st_rlx(st + i, 0ULL);
  for (size_t i = idx; i < 64 * 64; i += stride) {
    int d = i / 64, j = i % 64;
    w[OFF_WQT + j * 64 + d] = Wq[d * 64 + j];
  }
  for (size_t i = idx; i < 192 * 64; i += stride) {
    int o = i / 64, j = i % 64;
    w[OFF_WIH + j * 192 + o] = Wih[o * 64 + j];
    w[OFF_WHH + j * 192 + o] = Whh[o * 64 + j];
  }
  for (size_t i = idx; i < 128 * 64; i += stride) {
    int o = i / 64, j = i % 64;
    w[OFF_F1T + j * 128 + o] = f1[o * 64 + j];
  }
  for (size_t i = idx; i < 64 * 128; i += stride) {
    int d = i / 128, j = i % 128;
    w[OFF_F2T + j * 64 + d] = f2[d * 128 + j];
  }
}

__launch_bounds__(1024, 4)
__global__ void slot_attn_kernel(
    const float* __restrict__ inputs, const float* __restrict__ sinit,
    const float* __restrict__ smu, const float* __restrict__ slsig,
    const float* __restrict__ Wk, const float* __restrict__ Wv,
    const float* __restrict__ gbih, const float* __restrict__ gbhh,
    const float* __restrict__ fc1b, const float* __restrict__ fc2b,
    const float* __restrict__ lin_g, const float* __restrict__ lin_b,
    const float* __restrict__ lsl_g, const float* __restrict__ lsl_b,
    const float* __restrict__ lff_g, const float* __restrict__ lff_b,
    const float* __restrict__ wi_W, const float* __restrict__ wi_b,
    const float* __restrict__ wsW, const float* __restrict__ wsB,
    float* __restrict__ out, float* __restrict__ w) {
  __shared__ float s_slots[448];
  __shared__ float s_snl[448];
  __shared__ float s_q[448];
  __shared__ float s_scr1[1344];
  __shared__ float s_scr2[1344];
  __shared__ float s_updl[448];
  __shared__ float s_T[8192];       // [1024][8]
  __shared__ float s_pupd[7168];    // [16][7][64]
  __shared__ float s_z[48];         // z history [6][8]
  __shared__ float s_eb[8];         // exp(log_b)
  __shared__ float s_rb[8];         // 1/exp(log_b)
  __shared__ float s_q2[8];
  __shared__ float s_wl[8];
  __shared__ float s_redw[128];     // [16][8] wave partials (7-val exchanges)
  __shared__ float s_gath[128];     // [16][8] gathered block partials
  __shared__ float s_mw[3360];      // [16][210] wave partials (mega)
  __shared__ float s_M[216];        // mega totals: gv5(7), c5(7), M5..M2(4x49)
  __shared__ float s_gva[48];       // gv_i vectors, stride 8, i=1..5
  __shared__ float s_misc[4];

  const int tid = threadIdx.x;
  const int lane = tid & 63, wid = tid >> 6;
  const int bb = blockIdx.x & 15;   // batch
  const int ib16 = blockIdx.x >> 4; // 0..15 within batch group
  const size_t grow = (size_t)bb * CN + (size_t)ib16 * 1024 + tid;
  u64x* st = reinterpret_cast<u64x*>(w);
  float lg;

  // ================= phase 0: LN + k/v/logit projections (block-local rows) ==
  {
    const float* xin = inputs + grow * 64;
    float4 xa[16];
#pragma unroll
    for (int c = 0; c < 16; ++c) xa[c] = reinterpret_cast<const float4*>(xin)[c];
    float s1 = 0;
#pragma unroll
    for (int c = 0; c < 16; ++c) s1 += xa[c].x + xa[c].y + xa[c].z + xa[c].w;
    float mn = s1 * (1.f / 64.f);
    float s2 = 0;
#pragma unroll
    for (int c = 0; c < 16; ++c) {
      float dx = xa[c].x - mn, dy = xa[c].y - mn, dz = xa[c].z - mn, dw = xa[c].w - mn;
      s2 += dx * dx + dy * dy + dz * dz + dw * dw;
    }
    float rs = rsqrtf(s2 * (1.f / 64.f) + 1e-5f);
#pragma unroll
    for (int c = 0; c < 16; ++c) {
      float4 g4 = reinterpret_cast<const float4*>(lin_g)[c];
      float4 b4 = reinterpret_cast<const float4*>(lin_b)[c];
      xa[c].x = (xa[c].x - mn) * rs * g4.x + b4.x;
      xa[c].y = (xa[c].y - mn) * rs * g4.y + b4.y;
      xa[c].z = (xa[c].z - mn) * rs * g4.z + b4.z;
      xa[c].w = (xa[c].w - mn) * rs * g4.w + b4.w;
    }
    lg = wi_b[0];
#pragma unroll
    for (int c = 0; c < 16; ++c) lg += dot4(xa[c], reinterpret_cast<const float4*>(wi_W)[c]);
#pragma unroll 1
    for (int half = 0; half < 2; ++half) {
      const float* W = half ? Wv : Wk;
      float* ob = w + (half ? OFF_V : OFF_K) + grow * 64;
#pragma unroll 1
      for (int oc = 0; oc < 8; ++oc) {
        float acc[8] = {0, 0, 0, 0, 0, 0, 0, 0};
#pragma unroll
        for (int c = 0; c < 16; ++c) {
          float4 xv = xa[c];
#pragma unroll
          for (int o8 = 0; o8 < 8; ++o8) {
            float4 w4 = reinterpret_cast<const float4*>(W + (size_t)(oc * 8 + o8) * 64)[c];
            acc[o8] += dot4(xv, w4);
          }
        }
        reinterpret_cast<float4*>(ob + oc * 8)[0] = make_float4(acc[0], acc[1], acc[2], acc[3]);
        reinterpret_cast<float4*>(ob + oc * 8)[1] = make_float4(acc[4], acc[5], acc[6], acc[7]);
      }
    }
    // block-local softmax stats for 'a'
    float mx = lg;
#pragma unroll
    for (int m = 1; m < 64; m <<= 1) mx = fmaxf(mx, __shfl_xor(mx, m, 64));
    float se = wsum64(__expf(lg - mx));
    if (lane == 0) { s_redw[wid * 8 + 0] = mx; s_redw[wid * 8 + 1] = se; }
    asm volatile("s_waitcnt vmcnt(0)" ::: "memory");
    __syncthreads();
    if (wid == 0) {
      float m0 = (lane < 16) ? s_redw[lane * 8 + 0] : -1e30f;
      float e0 = (lane < 16) ? s_redw[lane * 8 + 1] : 0.f;
#pragma unroll
      for (int mm = 1; mm < 16; mm <<= 1) {
        float m1 = __shfl_xor(m0, mm, 64), e1 = __shfl_xor(e0, mm, 64);
        float nm = fmaxf(m0, m1);
        e0 = e0 * __expf(m0 - nm) + e1 * __expf(m1 - nm);
        m0 = nm;
      }
      if (lane == 0) {
        u64x* sp = st + ST1 + (size_t)(bb * 16 + ib16) * 2;
        st_rlx(sp + 0, pkf(m0, 1u));
        st_rlx(sp + 1, pkf(e0, 1u));
      }
    }
  }

  // ---- gather stats (sc1), compute global lse ----
  if (wid == 0) {
    int j = lane >> 2, f = lane & 3;
    if (f < 2) {
      s_gath[j * 4 + f] = poll_sc1(st + ST1 + (size_t)(bb * 16 + j) * 2 + f, 1u);
    }
  }
  __syncthreads();
  if (tid == 0) {
    float m = s_gath[0], se = s_gath[1];
#pragma unroll 1
    for (int j = 1; j < 16; ++j) {
      float mj = s_gath[j * 4], ej = s_gath[j * 4 + 1];
      float nm = fmaxf(m, mj);
      se = se * __expf(m - nm) + ej * __expf(mj - nm);
      m = nm;
    }
    s_misc[0] = m + __logf(se);
  }
  __syncthreads();
  const float aval = 7.f * __expf(lg - s_misc[0]);   // a[n] = 7*softmax(lg)

  unsigned e = 2;                    // epoch counter (stats used 1)
  float p[7], E[7], eu = 0.f;

  // ---- stamped 16-block all-reduce of 7 per-thread values (sc1) ----
  auto exchange = [&](float (&es)[7], float* dst, bool div_eb) {
#pragma unroll
    for (int m = 1; m < 64; m <<= 1) {
#pragma unroll
      for (int s = 0; s < 7; ++s) es[s] += __shfl_xor(es[s], m, 64);
    }
    if (lane == 0) {
#pragma unroll
      for (int s = 0; s < 7; ++s) s_redw[wid * 8 + s] = es[s];
    }
    __syncthreads();
    u64x* base = st + ST2 + ((size_t)(bb * 2 + (e & 1)) * 16) * 8;
    if (wid == 0 && lane < 7) {
      float bp = 0.f;
#pragma unroll
      for (int j = 0; j < 16; ++j) bp += s_redw[j * 8 + lane];
      st_rlx(base + (size_t)ib16 * 8 + lane, pkf(bp, e));
    }
    if (wid < 2) {
      int g = wid * 64 + lane;
      int j = g >> 3, s2 = g & 7;
      if (s2 < 7) s_gath[j * 8 + s2] = poll_sc1(base + (size_t)j * 8 + s2, e);
    }
    __syncthreads();
    if (tid < 7) {
      float tot = 0.f;
#pragma unroll
      for (int j = 0; j < 16; ++j) tot += s_gath[j * 8 + tid];
      dst[tid] = div_eb ? (s_eb[tid] / tot) : tot;
    }
    __syncthreads();
    ++e;
  };

  // factored sinkhorn forward: 5 iters; z history in s_z; leaves eu = a/t5
  auto fwd5 = [&]() {
#pragma unroll 1
    for (int i = 1; i <= 5; ++i) {
      float t = 0.f;
#pragma unroll
      for (int s = 0; s < 7; ++s) t += E[s] * s_z[(i - 1) * 8 + s];
      eu = aval / t;
      float es[7];
#pragma unroll
      for (int s = 0; s < 7; ++s) es[s] = E[s] * eu;
      exchange(es, &s_z[i * 8], true);
    }
  };

  // wave-reduce an array of n values into this wave's s_mw slots
  auto wred = [&](const float* v, int n, int off) {
#pragma unroll 1
    for (int k = 0; k < n; ++k) {
      float x = v[k];
#pragma unroll
      for (int m = 1; m < 64; m <<= 1) x += __shfl_xor(x, m, 64);
      if (lane == 0) s_mw[wid * 210 + off + k] = x;
    }
  };

  // slot phase common: LN(slots)->snl, q into LDS, eb/rb from log_b
  auto slot_common = [&]() {
    if (wid < 7) {
      float h = s_slots[wid * 64 + lane];
      float m = wsum64(h) * (1.f / 64.f);
      float d0 = h - m;
      float va = wsum64(d0 * d0) * (1.f / 64.f);
      float sn = d0 * rsqrtf(va + 1e-5f) * lsl_g[lane] + lsl_b[lane];
      s_snl[wid * 64 + lane] = sn;
      float pw = wsum64(sn * wsW[lane]);
      if (lane == 0) s_wl[wid] = pw + wsB[0];
    }
    __syncthreads();
    if (tid < 448) {
      int s = tid >> 6, dd = tid & 63;
      float acc = 0;
#pragma unroll 4
      for (int j = 0; j < 64; ++j) acc += s_snl[s * 64 + j] * w[OFF_WQT + j * 64 + dd];
      s_q[s * 64 + dd] = acc;
    }
    __syncthreads();
    if (wid < 7) {
      float qv = s_q[wid * 64 + lane];
      float q2 = wsum64(qv * qv);
      if (lane == 0) s_q2[wid] = q2;
    }
    if (tid == 0) {
      float mx = -1e30f;
#pragma unroll
      for (int s = 0; s < 7; ++s) mx = fmaxf(mx, s_wl[s]);
      float se = 0;
#pragma unroll
      for (int s = 0; s < 7; ++s) se += __expf(s_wl[s] - mx);
      float lse = mx + __logf(se);
#pragma unroll
      for (int s = 0; s < 7; ++s) {
        float ebv = __expf(s_wl[s] - lse + LOG7);
        s_eb[s] = ebv;
        s_rb[s] = 1.f / ebv;
      }
    }
    __syncthreads();
  };

  // init slots
  if (tid < 448) {
    int dd = tid & 63;
    s_slots[tid] = smu[dd] + __expf(slsig[dd]) * sinit[(size_t)bb * 448 + tid];
  }
  __syncthreads();
  slot_common();

#pragma unroll 1
  for (int it = 0; it < 3; ++it) {
    // ---- C = -cdist(k, q); E = exp(p) ----
    {
      const float* kb = w + OFF_K + grow * 64;
      float4 ka[16];
#pragma unroll
      for (int c = 0; c < 16; ++c) ka[c] = reinterpret_cast<const float4*>(kb)[c];
      float k2 = 0;
#pragma unroll
      for (int c = 0; c < 16; ++c) k2 += dot4(ka[c], ka[c]);
#pragma unroll
      for (int s = 0; s < 7; ++s) {
        float kq = 0;
#pragma unroll
        for (int c = 0; c < 16; ++c)
          kq += dot4(ka[c], *reinterpret_cast<const float4*>(&s_q[s * 64 + c * 4]));
        float sq = k2 + s_q2[s] - 2.f * kq;
        p[s] = -sqrtf(fmaxf(sq, 0.f) + 1e-12f);
        E[s] = __expf(p[s]);
      }
    }
    if (tid < 8) s_z[tid] = 1.f;     // z_0 = exp(v_0) = 1
    __syncthreads();

    // ---- MESH: 4 iterations; backward collapsed to ONE epoch each ----
#pragma unroll 1
    for (int ms = 0; ms < 4; ++ms) {
      fwd5();
      // per-row forward-state quantities; wave-partials for the mega reduce
      float g7[7], gTs = 0.f;
      {
        float t5 = 0.f;
#pragma unroll
        for (int s = 0; s < 7; ++s) t5 += E[s] * s_z[32 + s];
        float rt5 = 1.f / t5, eu5 = aval * rt5;
        float va[14];
#pragma unroll
        for (int s = 0; s < 7; ++s) {
          float T = E[s] * eu5 * s_z[40 + s];
          float gg = -(__logf(T + EPST) + T / (T + EPST)) * T;
          g7[s] = gg; gTs += gg;
          va[s] = gg;                               // gv5 partial
        }
#pragma unroll
        for (int s = 0; s < 7; ++s)
          va[7 + s] = gTs * (E[s] * s_z[32 + s] * rt5);   // c5 partial (sign later)
        wred(va, 14, 0);
#pragma unroll 1
        for (int i = 5; i >= 2; --i) {
          float t = 0.f;
#pragma unroll
          for (int s = 0; s < 7; ++s) t += E[s] * s_z[(i - 1) * 8 + s];
          float rt = 1.f / t, eui = aval * rt;
          float sn[7], sg[7];
#pragma unroll
          for (int s = 0; s < 7; ++s) {
            sn[s] = E[s] * eui * s_z[i * 8 + s] * s_rb[s];
            sg[s] = E[s] * s_z[(i - 1) * 8 + s] * rt;
          }
          int off = 14 + (5 - i) * 49;
          float vb[28];
#pragma unroll
          for (int s = 0; s < 4; ++s)
#pragma unroll
            for (int s2 = 0; s2 < 7; ++s2) vb[s * 7 + s2] = sn[s2] * sg[s];
          wred(vb, 28, off);
          float vc[21];
#pragma unroll
          for (int s = 4; s < 7; ++s)
#pragma unroll
            for (int s2 = 0; s2 < 7; ++s2) vc[(s - 4) * 7 + s2] = sn[s2] * sg[s];
          wred(vc, 21, off + 28);
        }
      }
      __syncthreads();
      // block-reduce wave partials; ONE cross-block exchange (210 values)
      {
        u64x* b4 = st + ST4 + ((size_t)(bb * 2 + (e & 1)) * 16) * 256;
        if (tid < 210) {
          float t = 0.f;
#pragma unroll
          for (int j = 0; j < 16; ++j) t += s_mw[j * 210 + tid];
          st_rlx(b4 + (size_t)ib16 * 256 + tid, pkf(t, e));
          float tot; bool ok;
          do {
            tot = 0.f; ok = true;
#pragma unroll
            for (int j = 0; j < 16; ++j) {
              u64x q = ld_rlx(b4 + (size_t)j * 256 + tid);
              ok = ok && ((unsigned)(q >> 32) == e);
              tot += __uint_as_float((unsigned)q);
            }
            if (!ok) __builtin_amdgcn_s_sleep(1);
          } while (!ok);
          s_M[tid] = tot;
        }
        __syncthreads();
        ++e;
      }
      // gv chain: gv5 = s_M[0..6]; gv_{i-1} = -c5*δ_{i5} + M_i·gv_i (7x7 matvecs)
      if (tid == 0) {
        float gv[7];
#pragma unroll
        for (int s = 0; s < 7; ++s) { gv[s] = s_M[s]; s_gva[40 + s] = gv[s]; }
#pragma unroll 1
        for (int i = 5; i >= 2; --i) {
          float nv[7];
#pragma unroll
          for (int s = 0; s < 7; ++s) {
            float acc = (i == 5) ? -s_M[7 + s] : 0.f;
#pragma unroll
            for (int s2 = 0; s2 < 7; ++s2)
              acc += s_M[14 + (5 - i) * 49 + s * 7 + s2] * gv[s2];
            nv[s] = acc;
          }
#pragma unroll
          for (int s = 0; s < 7; ++s) { gv[s] = nv[s]; s_gva[(i - 1) * 8 + s] = nv[s]; }
        }
      }
      __syncthreads();
      // per-row gp accumulation + p update (no further syncs)
      {
        float gp[7];
#pragma unroll
        for (int s = 0; s < 7; ++s) gp[s] = g7[s];
#pragma unroll 1
        for (int i = 5; i >= 1; --i) {
          float t = 0.f;
#pragma unroll
          for (int s = 0; s < 7; ++s) t += E[s] * s_z[(i - 1) * 8 + s];
          float rt = 1.f / t, eui = aval * rt;
          float gu = (i == 5) ? gTs : 0.f;
#pragma unroll
          for (int s = 0; s < 7; ++s) {
            float sn = E[s] * eui * s_z[i * 8 + s] * s_rb[s];
            float gz = -s_gva[i * 8 + s] * sn;
            gp[s] += gz; gu += gz;
          }
#pragma unroll
          for (int s = 0; s < 7; ++s) {
            float sg = E[s] * s_z[(i - 1) * 8 + s] * rt;
            gp[s] += -gu * sg;
          }
        }
#pragma unroll
        for (int s = 0; s < 7; ++s) {
          p[s] -= 5.0f * gp[s];
          E[s] = __expf(p[s]);
        }
      }
      __syncthreads();                       // all s_z reads done before z0 update
      if (tid < 8) s_z[tid] = s_z[40 + tid]; // warm-start z0 = z5
      __syncthreads();
    }

    // ---- final sinkhorn (warm-started) -> attn row ----
    fwd5();
    float T7[7];
#pragma unroll
    for (int s = 0; s < 7; ++s) T7[s] = E[s] * eu * s_z[40 + s];
    if (it == 2) {
      size_t ab = 7168 + (size_t)(bb * 7) * CN + (size_t)ib16 * 1024 + tid;
#pragma unroll
      for (int s = 0; s < 7; ++s) out[ab + (size_t)s * CN] = T7[s];
    }
#pragma unroll
    for (int s = 0; s < 7; ++s) s_T[tid * 8 + s] = T7[s];
    __syncthreads();

    // ---- updates = attn @ v (per-wave column reduce, then group combine) ----
    {
      const float* vb = w + OFF_V + (grow - tid + wid * 64) * 64 + lane;
      float acc[7] = {0, 0, 0, 0, 0, 0, 0};
#pragma unroll 4
      for (int n = 0; n < 64; ++n) {
        float vv = vb[(size_t)n * 64];
        const float* tr = &s_T[(wid * 64 + n) * 8];
        acc[0] += tr[0] * vv; acc[1] += tr[1] * vv; acc[2] += tr[2] * vv;
        acc[3] += tr[3] * vv; acc[4] += tr[4] * vv; acc[5] += tr[5] * vv;
        acc[6] += tr[6] * vv;
      }
#pragma unroll
      for (int s = 0; s < 7; ++s) s_pupd[(wid * 7 + s) * 64 + lane] = acc[s];
    }
    __syncthreads();
    {
      u64x* b3 = st + ST3 + ((size_t)(bb * 2 + (e & 1)) * 16) * 448;
      if (tid < 448) {
        float t = 0;
#pragma unroll
        for (int w16 = 0; w16 < 16; ++w16) t += s_pupd[w16 * 448 + tid];
        st_rlx(b3 + (size_t)ib16 * 448 + tid, pkf(t, e));
        float tot; bool ok;
        do {
          tot = 0.f; ok = true;
#pragma unroll
          for (int j = 0; j < 16; ++j) {
            u64x q = ld_rlx(b3 + (size_t)j * 448 + tid);
            ok = ok && ((unsigned)(q >> 32) == e);
            tot += __uint_as_float((unsigned)q);
          }
          if (!ok) __builtin_amdgcn_s_sleep(1);
        } while (!ok);
        s_updl[tid] = tot;
      }
      __syncthreads();
      ++e;
    }

    // ---- GRU cell + FF (redundant per block) ----
    {
#pragma unroll 1
      for (int idx = tid; idx < 1344; idx += 1024) {
        int s = idx / 192, o = idx - s * 192;
        float g1 = gbih[o], g2 = gbhh[o];
#pragma unroll 4
        for (int j = 0; j < 64; ++j) {
          g1 += s_updl[s * 64 + j] * w[OFF_WIH + j * 192 + o];
          g2 += s_slots[s * 64 + j] * w[OFF_WHH + j * 192 + o];
        }
        s_scr1[s * 192 + o] = g1;
        s_scr2[s * 192 + o] = g2;
      }
      __syncthreads();
      if (tid < 448) {
        int s = tid >> 6, dd = tid & 63;
        float ir = s_scr1[s * 192 + dd],        hr = s_scr2[s * 192 + dd];
        float iz = s_scr1[s * 192 + 64 + dd],   hz = s_scr2[s * 192 + 64 + dd];
        float in_ = s_scr1[s * 192 + 128 + dd], hn = s_scr2[s * 192 + 128 + dd];
        float r = 1.f / (1.f + __expf(-(ir + hr)));
        float zz = 1.f / (1.f + __expf(-(iz + hz)));
        float nn = tanhf(in_ + r * hn);
        s_updl[s * 64 + dd] = (1.f - zz) * nn + zz * s_slots[s * 64 + dd];
      }
      __syncthreads();
      if (wid < 7) {
        float h = s_updl[wid * 64 + lane];
        float m = wsum64(h) * (1.f / 64.f);
        float d0 = h - m;
        float va = wsum64(d0 * d0) * (1.f / 64.f);
        s_snl[wid * 64 + lane] = d0 * rsqrtf(va + 1e-5f) * lff_g[lane] + lff_b[lane];
      }
      __syncthreads();
      if (tid < 896) {
        int s = tid >> 7, i2 = tid & 127;
        float a1 = fc1b[i2];
#pragma unroll 4
        for (int j = 0; j < 64; ++j) a1 += s_snl[s * 64 + j] * w[OFF_F1T + j * 128 + i2];
        s_scr1[s * 128 + i2] = fmaxf(a1, 0.f);
      }
      __syncthreads();
      if (tid < 448) {
        int s = tid >> 6, dd = tid & 63;
        float a2 = fc2b[dd];
#pragma unroll 4
        for (int i2 = 0; i2 < 128; ++i2) a2 += s_scr1[s * 128 + i2] * w[OFF_F2T + i2 * 64 + dd];
        s_slots[s * 64 + dd] = s_updl[s * 64 + dd] + a2;
      }
      __syncthreads();
    }
    if (it < 2) slot_common();
  }

  if (ib16 == 0 && tid < 448) out[(size_t)bb * 448 + tid] = s_slots[tid];
}

extern "C" void kernel_launch(void* const* d_in, const int* in_sizes, int n_in,
                              void* d_out, int out_size, void* d_ws, size_t ws_size,
                              hipStream_t stream) {
  (void)in_sizes; (void)n_in; (void)out_size; (void)ws_size;
  const float* inputs = (const float*)d_in[0];
  const float* sinit  = (const float*)d_in[1];
  const float* smu    = (const float*)d_in[2];
  const float* slsig  = (const float*)d_in[3];
  const float* Wq     = (const float*)d_in[4];
  const float* Wk     = (const float*)d_in[5];
  const float* Wv     = (const float*)d_in[6];
  const float* gWih   = (const float*)d_in[7];
  const float* gWhh   = (const float*)d_in[8];
  const float* gbih   = (const float*)d_in[9];
  const float* gbhh   = (const float*)d_in[10];
  const float* fc1W   = (const float*)d_in[11];
  const float* fc1b   = (const float*)d_in[12];
  const float* fc2W   = (const float*)d_in[13];
  const float* fc2b   = (const float*)d_in[14];
  const float* ling   = (const float*)d_in[15];
  const float* linb   = (const float*)d_in[16];
  const float* lslg   = (const float*)d_in[17];
  const float* lslb   = (const float*)d_in[18];
  const float* lffg   = (const float*)d_in[19];
  const float* lffb   = (const float*)d_in[20];
  const float* wiW    = (const float*)d_in[21];
  const float* wib    = (const float*)d_in[22];
  const float* wsW    = (const float*)d_in[23];
  const float* wsb    = (const float*)d_in[24];
  float* out = (float*)d_out;
  float* w   = (float*)d_ws;

  prep_kernel<<<dim3(64), dim3(256), 0, stream>>>(Wq, gWih, gWhh, fc1W, fc2W, w);
  slot_attn_kernel<<<dim3(256), dim3(1024), 0, stream>>>(
      inputs, sinit, smu, slsig, Wk, Wv, gbih, gbhh, fc1b, fc2b,
      ling, linb, lslg, lslb, lffg, lffb, wiW, wib, wsW, wsb, out, w);
}